// Round 4
// baseline (36.161 us; speedup 1.0000x reference)
//
#include <hip/hip_runtime.h>
#include <math.h>

#define TPB 256
#define NDIM 8

typedef float fvec4 __attribute__((ext_vector_type(4)));

__global__ __launch_bounds__(TPB) void vegas_map_kernel(
    const float* __restrict__ u,      // [n, 8]
    const float* __restrict__ grid,   // [8, gcols]
    float* __restrict__ x_out,        // [n, 8]
    float* __restrict__ lj_out,       // [n]
    int n, int gcols, float lj_const) // lj_const = 8 * ln(ninc)
{
    extern __shared__ float lds_grid[];   // 8 * gcols floats (32 KB for gcols=1001)
    const int ninc = gcols - 1;
    const int gtot4 = (NDIM * gcols) >> 2;

    // Stage grid table into LDS with 16B loads (coalesced, conflict-free).
    const fvec4* __restrict__ g4 = (const fvec4*)grid;
    fvec4* lds4 = (fvec4*)lds_grid;
    for (int t = threadIdx.x; t < gtot4; t += TPB)
        lds4[t] = g4[t];
    __syncthreads();

    const float fninc = (float)ninc;
    const fvec4* __restrict__ u4 = (const fvec4*)u;
    fvec4* __restrict__ x4 = (fvec4*)x_out;

    const int stride = gridDim.x * TPB;

    auto process = [&](fvec4 a, fvec4 b, int idx) {
        float uv[NDIM] = {a.x, a.y, a.z, a.w, b.x, b.y, b.z, b.w};
        float xv[NDIM];
        float prod = 1.0f;
        #pragma unroll
        for (int d = 0; d < NDIM; ++d) {
            float un  = uv[d] * fninc;
            int   iu  = (int)un;                 // trunc == floor (un >= 0)
            int   iuc = iu < ninc ? iu : (ninc - 1);
            float du  = un - (float)iuc;         // clamp trick: at edge du>=1 reproduces upper
            const float* row = lds_grid + d * gcols;  // d*gcols folds to imm offset
            float g0 = row[iuc];
            float g1 = row[iuc + 1];
            float h  = g1 - g0;                  // == inc[d][iuc] bit-exactly
            xv[d] = g0 + h * du;                 // edge case: g[999]+h*du == upper
            prod *= h;                           // fac product (ninc factor hoisted to lj_const)
        }
        fvec4 oa = {xv[0], xv[1], xv[2], xv[3]};
        fvec4 ob = {xv[4], xv[5], xv[6], xv[7]};
        __builtin_nontemporal_store(oa, x4 + 2 * idx);
        __builtin_nontemporal_store(ob, x4 + 2 * idx + 1);
        // sum_d log(h_d * ninc) = log(prod h_d) + 8*ln(ninc)
        __builtin_nontemporal_store(__logf(prod) + lj_const, lj_out + idx);
    };

    for (int p = blockIdx.x * TPB + threadIdx.x; p < n; p += 2 * stride) {
        const int q = p + stride;
        const bool hq = (q < n);
        // Issue all u loads up front (memory-level parallelism).
        fvec4 a0 = __builtin_nontemporal_load(u4 + 2 * p);
        fvec4 b0 = __builtin_nontemporal_load(u4 + 2 * p + 1);
        fvec4 a1 = a0, b1 = b0;
        if (hq) {
            a1 = __builtin_nontemporal_load(u4 + 2 * q);
            b1 = __builtin_nontemporal_load(u4 + 2 * q + 1);
        }
        process(a0, b0, p);
        if (hq) process(a1, b1, q);
    }
}

extern "C" void kernel_launch(void* const* d_in, const int* in_sizes, int n_in,
                              void* d_out, int out_size, void* d_ws, size_t ws_size,
                              hipStream_t stream) {
    const float* u    = (const float*)d_in[0];   // [N, 8]
    const float* grid = (const float*)d_in[1];   // [8, ninc+1]
    // d_in[2] = inc (recomputed as adjacent grid diffs), d_in[3] = ninc (derived)
    const int n     = in_sizes[0] / NDIM;
    const int gcols = in_sizes[1] / NDIM;        // ninc + 1
    const int ninc  = gcols - 1;

    float* x_out  = (float*)d_out;
    float* lj_out = (float*)d_out + (size_t)n * NDIM;

    const float lj_const = (float)(NDIM * log((double)ninc));

    int blocks = (n + TPB - 1) / TPB;
    if (blocks > 1280) blocks = 1280;            // 5 blocks/CU x 256 CUs, persistent
    size_t lds_bytes = (size_t)NDIM * gcols * sizeof(float);

    vegas_map_kernel<<<blocks, TPB, lds_bytes, stream>>>(u, grid, x_out, lj_out,
                                                         n, gcols, lj_const);
}

// Round 5
// 26.943 us; speedup vs baseline: 1.3421x; 1.3421x over previous
//
#include <hip/hip_runtime.h>
#include <math.h>

#define TPB 1024
#define NDIM 8

typedef float fvec4 __attribute__((ext_vector_type(4)));

__global__ __launch_bounds__(TPB) void vegas_map_kernel(
    const float* __restrict__ u,      // [n, 8]
    const float* __restrict__ grid,   // [8, gcols]
    float* __restrict__ x_out,        // [n, 8]
    float* __restrict__ lj_out,       // [n]
    int n, int gcols, float lj_const) // lj_const = 8 * ln(ninc)
{
    extern __shared__ float lds_grid[];   // 8 * gcols floats (32 KB for gcols=1001)
    const int ninc = gcols - 1;
    const int gtot4 = (NDIM * gcols) >> 2;

    // Stage grid table into LDS with 16B loads (coalesced, conflict-free).
    const fvec4* __restrict__ g4 = (const fvec4*)grid;
    fvec4* lds4 = (fvec4*)lds_grid;
    for (int t = threadIdx.x; t < gtot4; t += TPB)
        lds4[t] = g4[t];
    __syncthreads();

    const float fninc = (float)ninc;
    const fvec4* __restrict__ u4 = (const fvec4*)u;
    fvec4* __restrict__ x4 = (fvec4*)x_out;

    const int stride = gridDim.x * TPB;

    for (int p = blockIdx.x * TPB + threadIdx.x; p < n; p += stride) {
        fvec4 a = u4[2 * p];
        fvec4 b = u4[2 * p + 1];
        float uv[NDIM] = {a.x, a.y, a.z, a.w, b.x, b.y, b.z, b.w};
        float xv[NDIM];
        float prod = 1.0f;

        #pragma unroll
        for (int d = 0; d < NDIM; ++d) {
            float un  = uv[d] * fninc;
            int   iu  = (int)un;                 // trunc == floor (un >= 0)
            int   iuc = iu < ninc ? iu : (ninc - 1);
            float du  = un - (float)iuc;         // clamp trick: edge case reproduces upper
            const float* row = lds_grid + d * gcols;
            float g0 = row[iuc];
            float g1 = row[iuc + 1];             // adjacent -> ds_read2_b32 pair
            float h  = g1 - g0;                  // == inc[d][iuc] bit-exactly
            xv[d] = g0 + h * du;
            prod *= h;                           // ninc factor hoisted into lj_const
        }

        fvec4 oa = {xv[0], xv[1], xv[2], xv[3]};
        fvec4 ob = {xv[4], xv[5], xv[6], xv[7]};
        x4[2 * p]     = oa;
        x4[2 * p + 1] = ob;
        lj_out[p] = __logf(prod) + lj_const;     // sum(log) == log(prod) + 8*ln(ninc)
    }
}

extern "C" void kernel_launch(void* const* d_in, const int* in_sizes, int n_in,
                              void* d_out, int out_size, void* d_ws, size_t ws_size,
                              hipStream_t stream) {
    const float* u    = (const float*)d_in[0];   // [N, 8]
    const float* grid = (const float*)d_in[1];   // [8, ninc+1]
    // d_in[2] = inc (recomputed as adjacent grid diffs), d_in[3] = ninc (derived)
    const int n     = in_sizes[0] / NDIM;
    const int gcols = in_sizes[1] / NDIM;        // ninc + 1
    const int ninc  = gcols - 1;

    float* x_out  = (float*)d_out;
    float* lj_out = (float*)d_out + (size_t)n * NDIM;

    const float lj_const = (float)(NDIM * log((double)ninc));

    int blocks = (n + TPB - 1) / TPB;
    if (blocks > 512) blocks = 512;              // 2 blocks/CU x 256 CUs = 32 waves/CU
    size_t lds_bytes = (size_t)NDIM * gcols * sizeof(float);

    vegas_map_kernel<<<blocks, TPB, lds_bytes, stream>>>(u, grid, x_out, lj_out,
                                                         n, gcols, lj_const);
}